// Round 8
// baseline (231.972 us; speedup 1.0000x reference)
//
#include <hip/hip_runtime.h>
#include <hip/hip_cooperative_groups.h>

namespace cg = cooperative_groups;

// Problem constants (fixed by the reference):
//   B=4096, L=200, EMBEDDING_DIM=100, C=2 chunks of M=50, VOCAB=100000
constexpr int C_ = 2;
constexpr int M_ = 50;
constexpr int ED = 100;
constexpr float EPS = 1e-8f;

// tbl layout per row: (a0, a0*dw0, a1, a1*dw1)
//
// Measured session facts:
//  - R4: hand-rolled agent-scope spin barrier = ~240 us of coherence-storm
//    spin. Two-dispatch structure beat it. BUT R4 also measured the fixed
//    non-kernel overhead: dur_us - kernel_dur = 56.5 us (44 us ws poison
//    fill at HBM write roofline + ~12 us dispatch/sync overhead).
//  - R1/R2/R6: four structurally distinct two-kernel variants all 92.5-96 us
//    -> both kernels are near their floors; residual is kernel-boundary cost
//    (drain + 2nd dispatch + ramp). This round: single cooperative dispatch
//    with the runtime's grid.sync() (sanctioned path, unlike R4's spin).

// ---------------------------------------------------------------------------
// Cooperative fused kernel. Grid MUST be 1024 x 256 (4 blocks/CU, co-resident;
// hipLaunchCooperativeKernel validates). Phase A: 2 rows per quad (rows q and
// q+NQ, NQ = total quads = 65536), all loads issued up-front (12 outstanding
// dwordx4/thread). Prefetch phase-B indices into registers (independent of
// tbl). grid.sync(). Phase B: one wave per batch element, gather-reduce.
// Per-row accumulation order identical to the harness-verified R2/R6 kernels.
// ---------------------------------------------------------------------------
__global__ __launch_bounds__(256) void coop_kernel(
    const int*   __restrict__ idx,   // [B, L]
    const float* __restrict__ emb,   // [VOCAB, 100]
    const float* __restrict__ wgt,   // [100]
    const float* __restrict__ att,   // [100] = [2,50]
    float*       __restrict__ out,   // [B]
    float*       __restrict__ tbl,   // ws: [VOCAB * 4]
    int B, int L, int vocab)
{
    __shared__ float2 s_uw[ED];   // (attend_u[e], weights[e])
    __shared__ float  s_su[C_];   // 1 / max(||u_c||, eps)

    const int t = threadIdx.x;
    if (t < ED) s_uw[t] = make_float2(att[t], wgt[t]);
    __syncthreads();
    if (t < C_) {
        float ss = 0.f;
        #pragma unroll
        for (int m = 0; m < M_; ++m) { float v = s_uw[t * M_ + m].x; ss += v * v; }
        s_su[t] = 1.0f / fmaxf(sqrtf(ss), EPS);
    }
    __syncthreads();

    const int lane = t & 63;
    const int wv   = t >> 6;
    const int j    = t & 3;                         // float4 slot within quad
    const int NQ   = (gridDim.x * blockDim.x) >> 2; // total quads (65536)
    const int rA   = (blockIdx.x * blockDim.x + t) >> 2;  // quad id = first row
    const int rB   = rA + NQ;                             // second row
    const bool okA = (rA < vocab);
    const bool okB = (rB < vocab);

    // ---------------- phase A: row stats (no early return -- sync below) ----
    if (okA) {
        const float4* rpA = reinterpret_cast<const float4*>(emb + (long long)rA * ED);
        const float4* rpB = reinterpret_cast<const float4*>(emb + (long long)rB * ED);

        float4 va[6], vb[6];
        #pragma unroll
        for (int it = 0; it < 6; ++it) va[it] = rpA[4 * it + j];
        if (okB) {
            #pragma unroll
            for (int it = 0; it < 6; ++it) vb[it] = rpB[4 * it + j];
        }
        float4 ta, tb;
        if (j == 0) {
            ta = rpA[24];
            if (okB) tb = rpB[24];
        }

        float AsQ0 = 0.f, AdU0 = 0.f, AdW0 = 0.f, AsQ1 = 0.f, AdU1 = 0.f, AdW1 = 0.f;
        float BsQ0 = 0.f, BdU0 = 0.f, BdW0 = 0.f, BsQ1 = 0.f, BdU1 = 0.f, BdW1 = 0.f;

        #pragma unroll
        for (int it = 0; it < 6; ++it) {
            const float xsA[4] = { va[it].x, va[it].y, va[it].z, va[it].w };
            const float xsB[4] = { vb[it].x, vb[it].y, vb[it].z, vb[it].w };
            #pragma unroll
            for (int k = 0; k < 4; ++k) {
                const int ebase = 16 * it + k;    // element e = ebase + 4*j
                const float2 uw = s_uw[ebase + 4 * j];
                const float xA = xsA[k];
                const float xB = xsB[k];
                if (ebase + 12 < M_) {            // chunk 0 for every j
                    AsQ0 = fmaf(xA, xA, AsQ0); AdU0 = fmaf(xA, uw.x, AdU0); AdW0 = fmaf(xA, uw.y, AdW0);
                    BsQ0 = fmaf(xB, xB, BsQ0); BdU0 = fmaf(xB, uw.x, BdU0); BdW0 = fmaf(xB, uw.y, BdW0);
                } else if (ebase >= M_) {         // chunk 1 for every j
                    AsQ1 = fmaf(xA, xA, AsQ1); AdU1 = fmaf(xA, uw.x, AdU1); AdW1 = fmaf(xA, uw.y, AdW1);
                    BsQ1 = fmaf(xB, xB, BsQ1); BdU1 = fmaf(xB, uw.x, BdU1); BdW1 = fmaf(xB, uw.y, BdW1);
                } else {                          // straddle: j==0 chunk0, else chunk1
                    if (j == 0) {
                        AsQ0 = fmaf(xA, xA, AsQ0); AdU0 = fmaf(xA, uw.x, AdU0); AdW0 = fmaf(xA, uw.y, AdW0);
                        BsQ0 = fmaf(xB, xB, BsQ0); BdU0 = fmaf(xB, uw.x, BdU0); BdW0 = fmaf(xB, uw.y, BdW0);
                    } else {
                        AsQ1 = fmaf(xA, xA, AsQ1); AdU1 = fmaf(xA, uw.x, AdU1); AdW1 = fmaf(xA, uw.y, AdW1);
                        BsQ1 = fmaf(xB, xB, BsQ1); BdU1 = fmaf(xB, uw.x, BdU1); BdW1 = fmaf(xB, uw.y, BdW1);
                    }
                }
            }
        }
        if (j == 0) {                             // tail float4 #24: elements 96..99
            const float xsA[4] = { ta.x, ta.y, ta.z, ta.w };
            const float xsB[4] = { tb.x, tb.y, tb.z, tb.w };
            #pragma unroll
            for (int k = 0; k < 4; ++k) {
                const float2 uw = s_uw[96 + k];
                AsQ1 = fmaf(xsA[k], xsA[k], AsQ1); AdU1 = fmaf(xsA[k], uw.x, AdU1); AdW1 = fmaf(xsA[k], uw.y, AdW1);
                BsQ1 = fmaf(xsB[k], xsB[k], BsQ1); BdU1 = fmaf(xsB[k], uw.x, BdU1); BdW1 = fmaf(xsB[k], uw.y, BdW1);
            }
        }

        #pragma unroll
        for (int m = 1; m < 4; m <<= 1) {         // quad tree-reduce
            AsQ0 += __shfl_xor(AsQ0, m, 4); AdU0 += __shfl_xor(AdU0, m, 4); AdW0 += __shfl_xor(AdW0, m, 4);
            AsQ1 += __shfl_xor(AsQ1, m, 4); AdU1 += __shfl_xor(AdU1, m, 4); AdW1 += __shfl_xor(AdW1, m, 4);
            BsQ0 += __shfl_xor(BsQ0, m, 4); BdU0 += __shfl_xor(BdU0, m, 4); BdW0 += __shfl_xor(BdW0, m, 4);
            BsQ1 += __shfl_xor(BsQ1, m, 4); BdU1 += __shfl_xor(BdU1, m, 4); BdW1 += __shfl_xor(BdW1, m, 4);
        }

        if (j == 0) {
            {
                const float cos0 = AdU0 / fmaxf(sqrtf(AsQ0), EPS) * s_su[0];
                const float cos1 = AdU1 / fmaxf(sqrtf(AsQ1), EPS) * s_su[1];
                const float a0 = __expf(cos0);
                const float a1 = __expf(cos1);
                reinterpret_cast<float4*>(tbl)[rA] = make_float4(a0, a0 * AdW0, a1, a1 * AdW1);
            }
            if (okB) {
                const float cos0 = BdU0 / fmaxf(sqrtf(BsQ0), EPS) * s_su[0];
                const float cos1 = BdU1 / fmaxf(sqrtf(BsQ1), EPS) * s_su[1];
                const float a0 = __expf(cos0);
                const float a1 = __expf(cos1);
                reinterpret_cast<float4*>(tbl)[rB] = make_float4(a0, a0 * BdW0, a1, a1 * BdW1);
            }
        }
    }

    // ------- prefetch phase-B indices into registers (independent of tbl) ---
    const int  b      = blockIdx.x * 4 + wv;      // one wave per batch element
    const bool bvalid = (b < B);
    const int* ib     = idx + (long long)b * L;
    int pre[4];
    #pragma unroll
    for (int m = 0; m < 4; ++m) {
        const int l = lane + 64 * m;
        pre[m] = (bvalid && l < L) ? ib[l] : 0;
    }

    // ---------------- grid-wide barrier (runtime cooperative sync) ----------
    __threadfence();
    cg::this_grid().sync();

    // ---------------- phase B: gather-reduce per batch element --------------
    if (bvalid) {
        float a0 = 0.f, ap0 = 0.f, a1 = 0.f, ap1 = 0.f;
        const float4* tb4 = reinterpret_cast<const float4*>(tbl);
        #pragma unroll
        for (int m = 0; m < 4; ++m) {
            const int l = lane + 64 * m;
            if (l < L) {
                const float4 v = tb4[pre[m]];
                a0 += v.x; ap0 += v.y; a1 += v.z; ap1 += v.w;
            }
        }
        for (int l = lane + 256; l < L; l += 64) {   // generic L fallback
            const float4 v = tb4[ib[l]];
            a0 += v.x; ap0 += v.y; a1 += v.z; ap1 += v.w;
        }
        #pragma unroll
        for (int off = 32; off > 0; off >>= 1) {
            a0  += __shfl_down(a0,  off, 64);
            a1  += __shfl_down(a1,  off, 64);
            ap0 += __shfl_down(ap0, off, 64);
            ap1 += __shfl_down(ap1, off, 64);
        }
        if (lane == 0) out[b] = ap0 / a0 + ap1 / a1;
    }
}

// ---------------------------------------------------------------------------
// Fallback two-kernel path (harness-verified R6 structure).
// ---------------------------------------------------------------------------
__global__ __launch_bounds__(256) void row_stats_kernel(
    const float* __restrict__ emb, const float* __restrict__ wgt,
    const float* __restrict__ att, float* __restrict__ tbl, int vocab)
{
    __shared__ float2 s_uw[ED];
    __shared__ float  s_su[C_];
    const int t = threadIdx.x;
    if (t < ED) s_uw[t] = make_float2(att[t], wgt[t]);
    __syncthreads();
    if (t < C_) {
        float ss = 0.f;
        #pragma unroll
        for (int m = 0; m < M_; ++m) { float v = s_uw[t * M_ + m].x; ss += v * v; }
        s_su[t] = 1.0f / fmaxf(sqrtf(ss), EPS);
    }
    __syncthreads();
    const int wave = t >> 6, lane = t & 63, g = lane >> 2, j = lane & 3;
    const int r = blockIdx.x * 64 + wave * 16 + g;
    if (r >= vocab) return;
    const float4* rowp = reinterpret_cast<const float4*>(emb + (long long)r * ED);
    float sq0 = 0.f, du0 = 0.f, dw0 = 0.f, sq1 = 0.f, du1 = 0.f, dw1 = 0.f;
    #pragma unroll
    for (int it = 0; it < 6; ++it) {
        const float4 v = rowp[4 * it + j];
        const float xs[4] = { v.x, v.y, v.z, v.w };
        #pragma unroll
        for (int k = 0; k < 4; ++k) {
            const int ebase = 16 * it + k;
            const float x = xs[k];
            const float2 uw = s_uw[ebase + 4 * j];
            if (ebase + 12 < M_)      { sq0 = fmaf(x,x,sq0); du0 = fmaf(x,uw.x,du0); dw0 = fmaf(x,uw.y,dw0); }
            else if (ebase >= M_)     { sq1 = fmaf(x,x,sq1); du1 = fmaf(x,uw.x,du1); dw1 = fmaf(x,uw.y,dw1); }
            else if (j == 0)          { sq0 = fmaf(x,x,sq0); du0 = fmaf(x,uw.x,du0); dw0 = fmaf(x,uw.y,dw0); }
            else                      { sq1 = fmaf(x,x,sq1); du1 = fmaf(x,uw.x,du1); dw1 = fmaf(x,uw.y,dw1); }
        }
    }
    if (j == 0) {
        const float4 v = rowp[24];
        const float xs[4] = { v.x, v.y, v.z, v.w };
        #pragma unroll
        for (int k = 0; k < 4; ++k) {
            const float2 uw = s_uw[96 + k];
            sq1 = fmaf(xs[k],xs[k],sq1); du1 = fmaf(xs[k],uw.x,du1); dw1 = fmaf(xs[k],uw.y,dw1);
        }
    }
    #pragma unroll
    for (int m = 1; m < 4; m <<= 1) {
        sq0 += __shfl_xor(sq0,m,4); du0 += __shfl_xor(du0,m,4); dw0 += __shfl_xor(dw0,m,4);
        sq1 += __shfl_xor(sq1,m,4); du1 += __shfl_xor(du1,m,4); dw1 += __shfl_xor(dw1,m,4);
    }
    if (j == 0) {
        const float cos0 = du0 / fmaxf(sqrtf(sq0), EPS) * s_su[0];
        const float cos1 = du1 / fmaxf(sqrtf(sq1), EPS) * s_su[1];
        const float a0 = __expf(cos0), a1 = __expf(cos1);
        reinterpret_cast<float4*>(tbl)[r] = make_float4(a0, a0 * dw0, a1, a1 * dw1);
    }
}

__global__ __launch_bounds__(256) void attend_kernel(
    const int* __restrict__ idx, const float4* __restrict__ tbl,
    float* __restrict__ out, int B, int L)
{
    const int wave = threadIdx.x >> 6, lane = threadIdx.x & 63;
    const int b = blockIdx.x * 4 + wave;
    if (b >= B) return;
    const int* ib = idx + (long long)b * L;
    float a0 = 0.f, a1 = 0.f, ap0 = 0.f, ap1 = 0.f;
    #pragma unroll 4
    for (int l = lane; l < L; l += 64) {
        const float4 v = tbl[ib[l]];
        a0 += v.x; ap0 += v.y; a1 += v.z; ap1 += v.w;
    }
    #pragma unroll
    for (int off = 32; off > 0; off >>= 1) {
        a0 += __shfl_down(a0,off,64); a1 += __shfl_down(a1,off,64);
        ap0 += __shfl_down(ap0,off,64); ap1 += __shfl_down(ap1,off,64);
    }
    if (lane == 0) out[b] = ap0 / a0 + ap1 / a1;
}

extern "C" void kernel_launch(void* const* d_in, const int* in_sizes, int n_in,
                              void* d_out, int out_size, void* d_ws, size_t ws_size,
                              hipStream_t stream) {
    const int*   idx = (const int*)d_in[0];    // word_idxs [4096,200] int32
    const float* emb = (const float*)d_in[1];  // emb_table [100000,100] f32
    const float* wgt = (const float*)d_in[2];  // weights   [100,1] f32
    const float* att = (const float*)d_in[3];  // attend_u  [2,50] f32
    float* out = (float*)d_out;                // [4096] f32

    const int B     = out_size;                 // 4096
    const int L     = in_sizes[0] / B;          // 200
    const int vocab = in_sizes[1] / ED;         // 100000

    float* tbl = (float*)d_ws;                  // vocab * 16 B scratch

    // Cooperative single-dispatch path: grid 1024x256 (4 blocks/CU,
    // co-resident). Requires B <= 4096 (phase-B coverage) and
    // vocab <= 131072 (2 rows/quad capacity).
    static int coop_ok = -1;
    if (coop_ok < 0) {
        int dev = 0, attr = 0;
        hipGetDevice(&dev);
        hipDeviceGetAttribute(&attr, hipDeviceAttributeCooperativeLaunch, dev);
        coop_ok = attr;
    }

    if (coop_ok && B <= 4096 && vocab <= 131072 && L <= 256 * 64) {
        int Bv = B, Lv = L, Vv = vocab;
        const int*   a0 = idx;  const float* a1 = emb;  const float* a2 = wgt;
        const float* a3 = att;  float* a4 = out;        float* a5 = tbl;
        void* args[] = { &a0, &a1, &a2, &a3, &a4, &a5, &Bv, &Lv, &Vv };
        hipError_t e = hipLaunchCooperativeKernel(
            (const void*)coop_kernel, dim3(1024), dim3(256), args, 0, stream);
        if (e == hipSuccess) return;
        // fall through to the two-kernel path on any launch failure
    }

    row_stats_kernel<<<(vocab + 63) / 64, 256, 0, stream>>>(emb, wgt, att, tbl, vocab);
    attend_kernel<<<(B + 3) / 4, 256, 0, stream>>>(idx, (const float4*)tbl, out, B, L);
}

// Round 9
// 130.824 us; speedup vs baseline: 1.7732x; 1.7732x over previous
//
#include <hip/hip_runtime.h>

// Problem constants (fixed by the reference):
//   B=4096, L=200, EMBEDDING_DIM=100, C=2 chunks of M=50, VOCAB=100000
constexpr int C_ = 2;
constexpr int M_ = 50;
constexpr int ED = 100;
constexpr float EPS = 1e-8f;

// Session facts (measured):
//  - R4 hand-rolled spin barrier: ~240 us idle. R8 hipLaunchCooperativeKernel
//    grid.sync(): ~115 us idle. ANY grid barrier at ~1024 blocks is >100 us
//    on gfx950 -> fusion-via-barrier is dead.
//  - ~44 us harness poison fill + ~12 us/dispatch overhead are in the timed
//    window and immovable from kernel code.
//  - R8 coop FETCH_SIZE = 27.7 MB < 40 MB table: L3 retains much of emb
//    across iterations -> gathered re-reads are L3-served.
//
// This kernel: ONE dispatch, NO barrier, NO workspace. Stats are recomputed
// inline per (b,l) occurrence (8.2x logical read amplification, absorbed by
// L2/L3; HBM still sees only the ~40 MB of unique rows). Removes pass-2's
// tbl round-trip and the inter-kernel dispatch boundary.
//
// Layout: one WAVE per batch element b. Within a wave, lane quad g handles
// gathered row l = base + 16*i + g; lane j of the quad reads float4 slots
// f = j + 4k (4 lanes -> consecutive float4s -> full 64B lines). u/w
// fragments for exactly those slots are preloaded into registers (14 float4,
// loaded once). Chunk membership by k is compile-time except the k==3, j==0
// straddle (elements 48..51) -- same classification as the harness-verified
// R2/R6 kernels. Quad xor-reduce -> cos -> exp -> accumulate. All 4 quad
// lanes accumulate identical values; the x4 scaling cancels EXACTLY in the
// AP/A ratios (power-of-2 scaling commutes with fp add). Final 64-lane
// xor-reduce, lane 0 writes out[b].
__global__ __launch_bounds__(256) void fused_direct_kernel(
    const int*   __restrict__ idx,   // [B, L]
    const float* __restrict__ emb,   // [VOCAB, 100]
    const float* __restrict__ wgt,   // [100]
    const float* __restrict__ att,   // [100] = [2,50]
    float*       __restrict__ out,   // [B]
    int B, int L)
{
    __shared__ float s_su[C_];       // 1 / max(||u_c||, eps)

    const int t = threadIdx.x;
    if (t < C_) {
        float ss = 0.f;
        #pragma unroll
        for (int m = 0; m < M_; ++m) { const float v = att[t * M_ + m]; ss += v * v; }
        s_su[t] = 1.0f / fmaxf(sqrtf(ss), EPS);
    }
    __syncthreads();

    const int wv   = t >> 6;
    const int lane = t & 63;
    const int g    = lane >> 2;      // quad id (0..15) = row slot within 16-row batch
    const int j    = lane & 3;       // float4 slot within quad
    const int b    = blockIdx.x * 4 + wv;
    if (b >= B) return;              // after the only __syncthreads

    const float su0 = s_su[0], su1 = s_su[1];

    // Per-lane u/w fragments: slot f = j + 4k covers elements e = 4f..4f+3.
    // k<=5 valid for all j; k==6 (f=24, e=96..99) only for j==0.
    const float4* att4 = reinterpret_cast<const float4*>(att);
    const float4* wgt4 = reinterpret_cast<const float4*>(wgt);
    float4 uf[7], wf[7];
    #pragma unroll
    for (int k = 0; k < 7; ++k) {
        const int f = j + 4 * k;
        if (f < 25) { uf[k] = att4[f]; wf[k] = wgt4[f]; }
        else        { uf[k] = make_float4(0.f,0.f,0.f,0.f); wf[k] = uf[k]; }
    }

    const int*    ib   = idx + (long long)b * L;
    const float4* emb4 = reinterpret_cast<const float4*>(emb);

    float A0 = 0.f, AP0 = 0.f, A1 = 0.f, AP1 = 0.f;

    for (int base = 0; base < L; base += 256) {
        // coalesced idx prefetch: 256 indices into 4 regs/lane
        int pre[4];
        #pragma unroll
        for (int m = 0; m < 4; ++m) {
            const int l0 = base + 64 * m + lane;
            pre[m] = (l0 < L) ? ib[l0] : 0;
        }
        #pragma unroll
        for (int i = 0; i < 16; ++i) {           // 16 rows per iteration
            if (base + 16 * i >= L) break;       // wave-uniform exit
            // row index for this quad, from the prefetched registers
            // (i is compile-time under the unroll -> pre[i>>2] is static)
            const int ridx = __shfl(pre[i >> 2], 16 * (i & 3) + g, 64);
            const int l    = base + 16 * i + g;
            if (l < L) {
                const float4* rp = emb4 + (long long)ridx * 25;
                float4 rv[7];
                #pragma unroll
                for (int k = 0; k < 6; ++k) rv[k] = rp[j + 4 * k];
                if (j == 0) rv[6] = rp[24];

                float sq0 = 0.f, du0 = 0.f, dw0 = 0.f;
                float sq1 = 0.f, du1 = 0.f, dw1 = 0.f;
                #pragma unroll
                for (int k = 0; k < 6; ++k) {
                    const float xs[4] = { rv[k].x, rv[k].y, rv[k].z, rv[k].w };
                    const float us[4] = { uf[k].x, uf[k].y, uf[k].z, uf[k].w };
                    const float ws[4] = { wf[k].x, wf[k].y, wf[k].z, wf[k].w };
                    #pragma unroll
                    for (int c = 0; c < 4; ++c) {
                        const float x = xs[c];
                        if (k <= 2) {            // e = 4j+16k+c <= 47: chunk 0
                            sq0 = fmaf(x, x, sq0); du0 = fmaf(x, us[c], du0); dw0 = fmaf(x, ws[c], dw0);
                        } else if (k >= 4) {     // e >= 64: chunk 1
                            sq1 = fmaf(x, x, sq1); du1 = fmaf(x, us[c], du1); dw1 = fmaf(x, ws[c], dw1);
                        } else {                 // k==3: e = 48+4j+c straddles at j==0
                            if (j == 0 && c < 2) { sq0 = fmaf(x, x, sq0); du0 = fmaf(x, us[c], du0); dw0 = fmaf(x, ws[c], dw0); }
                            else                 { sq1 = fmaf(x, x, sq1); du1 = fmaf(x, us[c], du1); dw1 = fmaf(x, ws[c], dw1); }
                        }
                    }
                }
                if (j == 0) {                    // k==6: e = 96..99, chunk 1
                    const float xs[4] = { rv[6].x, rv[6].y, rv[6].z, rv[6].w };
                    const float us[4] = { uf[6].x, uf[6].y, uf[6].z, uf[6].w };
                    const float ws[4] = { wf[6].x, wf[6].y, wf[6].z, wf[6].w };
                    #pragma unroll
                    for (int c = 0; c < 4; ++c) {
                        sq1 = fmaf(xs[c], xs[c], sq1); du1 = fmaf(xs[c], us[c], du1); dw1 = fmaf(xs[c], ws[c], dw1);
                    }
                }

                // quad tree-reduce: all 4 lanes end with the row totals
                #pragma unroll
                for (int m = 1; m < 4; m <<= 1) {
                    sq0 += __shfl_xor(sq0, m, 4); du0 += __shfl_xor(du0, m, 4); dw0 += __shfl_xor(dw0, m, 4);
                    sq1 += __shfl_xor(sq1, m, 4); du1 += __shfl_xor(du1, m, 4); dw1 += __shfl_xor(dw1, m, 4);
                }

                const float a0 = __expf(du0 / fmaxf(sqrtf(sq0), EPS) * su0);
                const float a1 = __expf(du1 / fmaxf(sqrtf(sq1), EPS) * su1);
                // all 4 quad lanes accumulate (x4 factor cancels in the ratios)
                A0 += a0; AP0 = fmaf(a0, dw0, AP0);
                A1 += a1; AP1 = fmaf(a1, dw1, AP1);
            }
        }
    }

    // 64-lane reduce of the per-lane partials
    #pragma unroll
    for (int off = 1; off < 64; off <<= 1) {
        A0  += __shfl_xor(A0,  off, 64);
        AP0 += __shfl_xor(AP0, off, 64);
        A1  += __shfl_xor(A1,  off, 64);
        AP1 += __shfl_xor(AP1, off, 64);
    }
    if (lane == 0) out[b] = AP0 / A0 + AP1 / A1;
}

extern "C" void kernel_launch(void* const* d_in, const int* in_sizes, int n_in,
                              void* d_out, int out_size, void* d_ws, size_t ws_size,
                              hipStream_t stream) {
    const int*   idx = (const int*)d_in[0];    // word_idxs [4096,200] int32
    const float* emb = (const float*)d_in[1];  // emb_table [100000,100] f32
    const float* wgt = (const float*)d_in[2];  // weights   [100,1] f32
    const float* att = (const float*)d_in[3];  // attend_u  [2,50] f32
    float* out = (float*)d_out;                // [4096] f32

    const int B = out_size;                    // 4096
    const int L = in_sizes[0] / B;             // 200

    fused_direct_kernel<<<(B + 3) / 4, 256, 0, stream>>>(idx, emb, wgt, att, out, B, L);
}